// Round 1
// baseline (190.523 us; speedup 1.0000x reference)
//
#include <hip/hip_runtime.h>

// Problem constants (fixed by the harness shapes)
#define BB      8
#define LL      8192
#define DD      512
#define NCHUNK  1024      // num_chunks in compressed_x
#define TC      64        // time-chunk length for the hierarchical scan
#define NC      (LL/TC)   // 128 time-chunks per batch row

// ---------------------------------------------------------------------------
// Kernel 1: per-batch-row boundary cumsum -> effective chunk index per t.
// idx_eff[b][t] = chunk index to gather, or -1 meaning e[t] = 0.
// One block per batch row, 256 threads, 32 contiguous t per thread.
// ---------------------------------------------------------------------------
__global__ __launch_bounds__(256)
void k_index(const float* __restrict__ bp, int* __restrict__ idx_eff) {
    const int b   = blockIdx.x;
    const int tid = threadIdx.x;              // 0..255
    const int PER = LL / 256;                 // 32
    const float* row = bp + (size_t)b * LL;
    const int base = tid * PER;

    int cnt_local = 0;
    for (int i = 0; i < PER; ++i)
        cnt_local += (row[base + i] > 0.5f) ? 1 : 0;

    __shared__ int s[256];
    s[tid] = cnt_local;
    __syncthreads();
    // Hillis-Steele inclusive scan over the 256 per-thread counts
    for (int off = 1; off < 256; off <<= 1) {
        int v = (tid >= off) ? s[tid - off] : 0;
        __syncthreads();
        s[tid] += v;
        __syncthreads();
    }
    const int excl  = (tid == 0) ? 0 : s[tid - 1];
    const int total = s[255];

    int* orow = idx_eff + (size_t)b * LL;
    if (total > 0) {
        int cnt = excl;
        for (int i = 0; i < PER; ++i) {
            const int t = base + i;
            cnt += (row[t] > 0.5f) ? 1 : 0;
            // valid iff 1 <= cnt <= NCHUNK; then idx = cnt-1 in [0, NCHUNK-1]
            orow[t] = (cnt >= 1 && cnt <= NCHUNK) ? (cnt - 1) : -1;
        }
    } else {
        // uniform fallback: step = LL/NCHUNK = 8, all t < NCHUNK*step valid
        for (int i = 0; i < PER; ++i) {
            const int t = base + i;
            orow[t] = t >> 3;
        }
    }
}

// ---------------------------------------------------------------------------
// Kernel 2: local chunk scan from zero state.
// For each (b, c): q[d] = state at chunk end assuming s_in = 0,
//                  Achunk = prod over chunk of (1 - a_eff[t]).
// a_eff[0] = 1 implements s[0] = e[0].
// ---------------------------------------------------------------------------
__global__ __launch_bounds__(512)
void k_local(const float* __restrict__ cx, const float* __restrict__ bp,
             const int* __restrict__ idx_eff,
             float* __restrict__ Qend, float* __restrict__ Achunk) {
    const int blk = blockIdx.x;               // b*NC + c
    const int b = blk / NC, c = blk % NC;
    const int d = threadIdx.x;                // 0..511

    __shared__ float a_s[TC];
    __shared__ int   i_s[TC];
    if (d < TC) {
        const int t = c * TC + d;
        float a = bp[(size_t)b * LL + t];
        if (t == 0) a = 1.0f;
        a_s[d] = a;
        i_s[d] = idx_eff[(size_t)b * LL + t];
    }
    __syncthreads();

    const float* cxb = cx + (size_t)b * NCHUNK * DD;
    float q = 0.0f;
    for (int i = 0; i < TC; ++i) {
        const float a  = a_s[i];
        const int  idx = i_s[i];
        const float e  = (idx >= 0) ? cxb[(size_t)idx * DD + d] : 0.0f;
        q = a * e + (1.0f - a) * q;
    }
    Qend[((size_t)b * NC + c) * DD + d] = q;

    if (d == 0) {
        float P = 1.0f;
        for (int i = 0; i < TC; ++i) P *= (1.0f - a_s[i]);
        Achunk[b * NC + c] = P;
    }
}

// ---------------------------------------------------------------------------
// Kernel 3: cross-chunk scan (sequential over NC=128 chunks, parallel in d).
// S0[b][c][d] = smoothed state entering chunk c.
// One block per batch, 512 threads (one per d).
// ---------------------------------------------------------------------------
__global__ __launch_bounds__(512)
void k_cross(const float* __restrict__ Qend, const float* __restrict__ Achunk,
             float* __restrict__ S0) {
    const int b = blockIdx.x;
    const int d = threadIdx.x;

    __shared__ float A_s[NC];
    if (d < NC) A_s[d] = Achunk[b * NC + d];
    __syncthreads();

    float s = 0.0f;
    for (int c = 0; c < NC; ++c) {
        const size_t o = ((size_t)b * NC + c) * DD + d;
        S0[o] = s;
        s = Qend[o] + A_s[c] * s;
    }
}

// ---------------------------------------------------------------------------
// Kernel 4: final pass — re-run the exact sequential recurrence within each
// chunk, seeded with S0, writing the output. Coalesced 2KB row per t.
// ---------------------------------------------------------------------------
__global__ __launch_bounds__(512)
void k_final(const float* __restrict__ cx, const float* __restrict__ bp,
             const int* __restrict__ idx_eff, const float* __restrict__ S0,
             float* __restrict__ out) {
    const int blk = blockIdx.x;               // b*NC + c
    const int b = blk / NC, c = blk % NC;
    const int d = threadIdx.x;

    __shared__ float a_s[TC];
    __shared__ int   i_s[TC];
    if (d < TC) {
        const int t = c * TC + d;
        float a = bp[(size_t)b * LL + t];
        if (t == 0) a = 1.0f;
        a_s[d] = a;
        i_s[d] = idx_eff[(size_t)b * LL + t];
    }
    __syncthreads();

    const float* cxb = cx + (size_t)b * NCHUNK * DD;
    float s = S0[((size_t)b * NC + c) * DD + d];
    float* orow = out + ((size_t)b * LL + (size_t)c * TC) * DD + d;

    for (int i = 0; i < TC; ++i) {
        const float a  = a_s[i];
        const int  idx = i_s[i];
        const float e  = (idx >= 0) ? cxb[(size_t)idx * DD + d] : 0.0f;
        s = a * e + (1.0f - a) * s;
        orow[(size_t)i * DD] = s;
    }
}

// ---------------------------------------------------------------------------
// Launcher
// ---------------------------------------------------------------------------
extern "C" void kernel_launch(void* const* d_in, const int* in_sizes, int n_in,
                              void* d_out, int out_size, void* d_ws, size_t ws_size,
                              hipStream_t stream) {
    const float* cx = (const float*)d_in[0];   // (B, NUM_CHUNKS, D) f32
    const float* bp = (const float*)d_in[1];   // (B, L) f32
    // d_in[2] = original_length (fixed 8192, baked into LL)
    float* out = (float*)d_out;                // (B, L, D) f32

    // Workspace layout (all offsets 4KB-aligned):
    //   idx_eff : int   [B][L]        262144 B
    //   Achunk  : float [B][NC]         4096 B
    //   Qend    : float [B][NC][D]   2097152 B
    //   S0      : float [B][NC][D]   2097152 B
    char* ws = (char*)d_ws;
    int*   idx_eff = (int*)(ws);
    float* Achunk  = (float*)(ws + 262144);
    float* Qend    = (float*)(ws + 266240);
    float* S0      = (float*)(ws + 2363392);

    k_index<<<BB,      256, 0, stream>>>(bp, idx_eff);
    k_local<<<BB * NC, 512, 0, stream>>>(cx, bp, idx_eff, Qend, Achunk);
    k_cross<<<BB,      512, 0, stream>>>(Qend, Achunk, S0);
    k_final<<<BB * NC, 512, 0, stream>>>(cx, bp, idx_eff, S0, out);
}